// Round 7
// baseline (199.418 us; speedup 1.0000x reference)
//
#include <hip/hip_runtime.h>

typedef __attribute__((ext_vector_type(4))) int i32x4;
typedef __attribute__((ext_vector_type(16))) int i32x16;

// ---------------------------------------------------------------------------
// Helpers
// ---------------------------------------------------------------------------
__device__ __forceinline__ void gload_lds16(const void* g, void* l) {
  // async global->LDS, 16B/lane. LDS dest must be wave-uniform base + lane*16.
  __builtin_amdgcn_global_load_lds((const __attribute__((address_space(1))) void*)g,
                                   (__attribute__((address_space(3))) void*)l,
                                   16, 0, 0);
}

#define BARRIER() __builtin_amdgcn_s_barrier()
#define LGKM0()   asm volatile("s_waitcnt lgkmcnt(0)" ::: "memory")
#define VMCNT0()  asm volatile("s_waitcnt vmcnt(0)" ::: "memory")

// ---------------------------------------------------------------------------
// Fused quantize f32 -> int8 for both x and w (round-half-even, clamp +-127)
// ---------------------------------------------------------------------------
__global__ void quant_both_kernel(const float* __restrict__ x,
                                  const float* __restrict__ w,
                                  signed char* __restrict__ qx,
                                  signed char* __restrict__ qw,
                                  const float* __restrict__ amax_x,
                                  const float* __restrict__ amax_w,
                                  int nx4, int nw4) {
  const float sx = 127.0f / amax_x[0];
  const float sw = 127.0f / amax_w[0];
  int i = blockIdx.x * blockDim.x + threadIdx.x;
  const int stride = gridDim.x * blockDim.x;
  const int ntot = nx4 + nw4;
  for (; i < ntot; i += stride) {
    const bool isx = i < nx4;
    const float4* src = isx ? (const float4*)x : (const float4*)w;
    int* dst = isx ? (int*)qx : (int*)qw;
    const int j = isx ? i : i - nx4;
    const float s = isx ? sx : sw;
    float4 v = src[j];
    int q0 = (int)rintf(fminf(fmaxf(v.x * s, -127.0f), 127.0f));
    int q1 = (int)rintf(fminf(fmaxf(v.y * s, -127.0f), 127.0f));
    int q2 = (int)rintf(fminf(fmaxf(v.z * s, -127.0f), 127.0f));
    int q3 = (int)rintf(fminf(fmaxf(v.w * s, -127.0f), 127.0f));
    dst[j] = (q0 & 255) | ((q1 & 255) << 8) | ((q2 & 255) << 16) | ((q3 & 255) << 24);
  }
}

// ---------------------------------------------------------------------------
// 256x256 8-phase int8 GEMM, k-split phases + mfma_i32_32x32x32_i8.
// out[N,M] = dequant(qx[N,K] . qw[M,K]^T) + bias
// 512 thr = 8 waves (2M x 4N), per-wave 128x64 via 4x2 frags of 32x32.
// BK=128 int8 = 4 k-slices of 32. Phase q: {read k-slice q (4A+2B b128);
// stage (P1/P2/P5/P6 only); barrier; lgkm0; 8 MFMA; [vmcnt0 @P4/P8]; barrier}.
// Even 6 reads/phase (was 12/4/8/0) -> LDS drain overlaps MFMA every phase.
// LDS 2dbuf x (A,B) x [256][128B] = 128 KiB. Swizzle: chunk' = chunk^(row&7),
// inverse on global source (rule #21), forward on ds_read. 0 conflicts.
// A/B frag layout (32x32x32): row(col) = lane&31, k = 16*(lane>>5)+0..15.
// C/D: col = lane&31, row = (reg&3) + 8*(reg>>2) + 4*(lane>>5)  [m74/m101].
// ---------------------------------------------------------------------------
__global__ __launch_bounds__(512, 2) void gemm_i8_ks(
    const signed char* __restrict__ qx,   // [N,K]
    const signed char* __restrict__ qw,   // [M,K]
    const float* __restrict__ bias,       // [M]
    const float* __restrict__ amax_x,
    const float* __restrict__ amax_w,
    float* __restrict__ out,              // [N,M]
    int N, int M, int K) {
  constexpr int BKB = 128;  // K bytes per tile

  __shared__ signed char lds[4][256 * 128];  // [A0,B0,A1,B1], 32 KiB each

  const int tid  = threadIdx.x;
  const int lane = tid & 63;
  const int wid  = tid >> 6;
  const int wm   = wid >> 2;   // 0..1
  const int wn   = wid & 3;    // 0..3
  const int l31  = lane & 31;
  const int l1   = lane >> 5;

  // bijective XCD-aware block swizzle (nwg = 512, divisible by 8)
  const int nbn = M >> 8;                      // 16
  const int nwg = (N >> 8) * nbn;              // 512
  const int cpx = nwg >> 3;
  const int swz = (blockIdx.x & 7) * cpx + (blockIdx.x >> 3);
  const int rowBase = (swz / nbn) << 8;
  const int colBase = (swz % nbn) << 8;

  // staging source pointers: thread t covers slots {h*1024 + L*512 + t};
  // logical (row = slot>>3, c = (slot&7) ^ (row&7)); LDS dest stays linear.
  const signed char* sA[2][2];
  const signed char* sB[2][2];
#pragma unroll
  for (int h = 0; h < 2; ++h)
#pragma unroll
    for (int L = 0; L < 2; ++L) {
      const int slot = h * 1024 + L * 512 + tid;
      const int row  = slot >> 3;
      const int c    = (slot & 7) ^ (row & 7);
      sA[h][L] = qx + (size_t)(rowBase + row) * K + c * 16;
      sB[h][L] = qw + (size_t)(colBase + row) * K + c * 16;
    }

  signed char* A0 = lds[0];
  signed char* B0 = lds[1];
  signed char* A1 = lds[2];
  signed char* B1 = lds[3];

#define STAGE(dst, src, h, kt)                                                \
  do {                                                                        \
    gload_lds16(src[h][0] + (kt) * BKB, (dst) + (h)*16384 + tid * 16);        \
    gload_lds16(src[h][1] + (kt) * BKB, (dst) + (h)*16384 + 8192 + tid * 16); \
  } while (0)

  // fragment-read addressing. Rows are mult of 32 + l31 -> row&7 == l31&7.
  // k-slice q occupies chunks {2q, 2q+1}; lane half l1 picks one.
  int ck[4];
#pragma unroll
  for (int q = 0; q < 4; ++q) ck[q] = ((2 * q + l1) ^ (l31 & 7)) * 16;
  const int aBase = (wm * 128 + l31) * 128;
  const int bBase = (wn * 64 + l31) * 128;

  i32x16 acc[4][2] = {{{0}}};
  i32x4 af[4];
  i32x4 bf[2];

#define RDQ(RA, RB, q)                                                        \
  {                                                                           \
    _Pragma("unroll") for (int mi = 0; mi < 4; ++mi)                          \
        af[mi] = *(const i32x4*)((RA) + aBase + mi * 4096 + ck[q]);           \
    _Pragma("unroll") for (int nj = 0; nj < 2; ++nj)                          \
        bf[nj] = *(const i32x4*)((RB) + bBase + nj * 4096 + ck[q]);           \
  }
#define MFMA8()                                                               \
  {                                                                           \
    __builtin_amdgcn_s_setprio(1);                                            \
    _Pragma("unroll") for (int mi = 0; mi < 4; ++mi)                          \
        _Pragma("unroll") for (int nj = 0; nj < 2; ++nj)                      \
            acc[mi][nj] = __builtin_amdgcn_mfma_i32_32x32x32_i8(              \
                af[mi], bf[nj], acc[mi][nj], 0, 0, 0);                        \
    __builtin_amdgcn_s_setprio(0);                                            \
  }

  const int T = K / BKB;  // 32 K-tiles

  // prologue: tile0 -> A0/B0 (8 loads/thread); drain; publish.
  STAGE(A0, sA, 0, 0); STAGE(A0, sA, 1, 0);
  STAGE(B0, sB, 0, 0); STAGE(B0, sB, 1, 0);
  VMCNT0();
  BARRIER();

  for (int it = 0; it < T / 2; ++it) {
    const int k1 = 2 * it + 1;                             // always valid
    const int k2 = (2 * it + 2 < T) ? 2 * it + 2 : T - 1;  // clamped, never read

    // P1-P4: consume A0/B0 (tile t), k-slices 0..3.
    // Stage A1/B1 <- t+1 in P1/P2 (A1/B1 dead since prev P8 barrier).
    RDQ(A0, B0, 0);
    STAGE(A1, sA, 0, k1); STAGE(B1, sB, 0, k1);
    BARRIER(); LGKM0(); MFMA8(); BARRIER();

    RDQ(A0, B0, 1);
    STAGE(A1, sA, 1, k1); STAGE(B1, sB, 1, k1);
    BARRIER(); LGKM0(); MFMA8(); BARRIER();

    RDQ(A0, B0, 2);
    BARRIER(); LGKM0(); MFMA8(); BARRIER();

    RDQ(A0, B0, 3);
    BARRIER(); LGKM0(); MFMA8();
    VMCNT0();   // drain A1/B1(t+1) staged P1/P2 (lead >= 2 phases)
    BARRIER();  // publish for P5

    // P5-P8: consume A1/B1 (tile t+1). Stage A0/B0 <- t+2 in P5/P6
    // (A0/B0 reads finished at P4's trailing barrier).
    RDQ(A1, B1, 0);
    STAGE(A0, sA, 0, k2); STAGE(B0, sB, 0, k2);
    BARRIER(); LGKM0(); MFMA8(); BARRIER();

    RDQ(A1, B1, 1);
    STAGE(A0, sA, 1, k2); STAGE(B0, sB, 1, k2);
    BARRIER(); LGKM0(); MFMA8(); BARRIER();

    RDQ(A1, B1, 2);
    BARRIER(); LGKM0(); MFMA8(); BARRIER();

    RDQ(A1, B1, 3);
    BARRIER(); LGKM0(); MFMA8();
    VMCNT0();   // drain A0/B0(t+2) staged P5/P6
    BARRIER();  // publish for next P1
  }

  VMCNT0();  // drain clamped tail stages before LDS goes dead

  // epilogue: dequant + bias.
  // C/D 32x32: col = lane&31, row = (reg&3) + 8*(reg>>2) + 4*(lane>>5)
  const float dq = amax_x[0] * amax_w[0] * (1.0f / (127.0f * 127.0f));
#pragma unroll
  for (int nj = 0; nj < 2; ++nj) {
    const int col = colBase + wn * 64 + nj * 32 + l31;
    const float bv = bias[col];
#pragma unroll
    for (int mi = 0; mi < 4; ++mi) {
      const int rowF = rowBase + wm * 128 + mi * 32 + 4 * l1;
#pragma unroll
      for (int r = 0; r < 16; ++r) {
        const int row = rowF + (r & 3) + 8 * (r >> 2);
        out[(size_t)row * M + col] = (float)acc[mi][nj][r] * dq + bv;
      }
    }
  }
#undef STAGE
#undef RDQ
#undef MFMA8
}

// ---------------------------------------------------------------------------
// Launch
// ---------------------------------------------------------------------------
extern "C" void kernel_launch(void* const* d_in, const int* in_sizes, int n_in,
                              void* d_out, int out_size, void* d_ws, size_t ws_size,
                              hipStream_t stream) {
  const float* x      = (const float*)d_in[0];
  const float* w      = (const float*)d_in[1];
  const float* bias   = (const float*)d_in[2];
  const float* amax_x = (const float*)d_in[3];
  const float* amax_w = (const float*)d_in[4];
  float* out = (float*)d_out;

  const int M = in_sizes[2];                    // 4096
  const int K = in_sizes[1] / M;                // 4096
  const int N = (int)((long)in_sizes[0] / K);   // 8192

  signed char* qx = (signed char*)d_ws;         // [N,K] int8
  signed char* qw = qx + (size_t)N * K;         // [M,K] int8

  const int nx4 = N * (K / 4);
  const int nw4 = M * (K / 4);
  quant_both_kernel<<<2048, 256, 0, stream>>>(x, w, qx, qw, amax_x, amax_w,
                                              nx4, nw4);

  const int nwg = (N / 256) * (M / 256);        // 512
  gemm_i8_ks<<<nwg, 512, 0, stream>>>(qx, qw, bias, amax_x, amax_w, out,
                                      N, M, K);
}